// Round 1
// baseline (26435.516 us; speedup 1.0000x reference)
//
#include <hip/hip_runtime.h>

// Problem constants (fixed by the reference)
#define N_PTS 32768
#define C_IN 128
#define C_OUTC 256
#define KNN_K 16
#define M_CL 8192
#define NCELLS 4096  // 16^3 spatial cells for the counting sort

// ---------------------------------------------------------------------------
// Spatial cell id: 16^3 grid over [-5,5]^3 (pos ~ N(0,1), |coord| < 5 w.h.p.;
// clamped otherwise). Used for a counting sort so each FPS thread owns 32
// spatially-coherent points -> tight bboxes -> effective culling.
// ---------------------------------------------------------------------------
__device__ __forceinline__ int cell_of(float x, float y, float z) {
  int ix = (int)((x + 5.0f) * 1.6f); ix = ix < 0 ? 0 : (ix > 15 ? 15 : ix);
  int iy = (int)((y + 5.0f) * 1.6f); iy = iy < 0 ? 0 : (iy > 15 ? 15 : iy);
  int iz = (int)((z + 5.0f) * 1.6f); iz = iz < 0 ? 0 : (iz > 15 ? 15 : iz);
  return (ix << 8) | (iy << 4) | iz;
}

__global__ void k_hist(const float* __restrict__ pos, int* __restrict__ hist) {
  int i = blockIdx.x * 256 + threadIdx.x;
  float x = pos[i * 3 + 0], y = pos[i * 3 + 1], z = pos[i * 3 + 2];
  atomicAdd(&hist[cell_of(x, y, z)], 1);
}

// Exclusive scan over 4096 cell counts; 1 block of 1024 threads, 4 cells each.
__global__ __launch_bounds__(1024) void k_scan(const int* __restrict__ hist,
                                               int* __restrict__ cursor) {
  __shared__ int sd[1024];
  const int tid = threadIdx.x;
  int c0 = hist[tid * 4 + 0], c1 = hist[tid * 4 + 1];
  int c2 = hist[tid * 4 + 2], c3 = hist[tid * 4 + 3];
  int s = c0 + c1 + c2 + c3;
  sd[tid] = s;
  __syncthreads();
  for (int off = 1; off < 1024; off <<= 1) {
    int v = (tid >= off) ? sd[tid - off] : 0;
    __syncthreads();
    sd[tid] += v;
    __syncthreads();
  }
  int excl = sd[tid] - s;
  cursor[tid * 4 + 0] = excl;
  cursor[tid * 4 + 1] = excl + c0;
  cursor[tid * 4 + 2] = excl + c0 + c1;
  cursor[tid * 4 + 3] = excl + c0 + c1 + c2;
}

__global__ void k_scatter(const float* __restrict__ pos, int* __restrict__ cursor,
                          float* __restrict__ spx, float* __restrict__ spy,
                          float* __restrict__ spz, int* __restrict__ sorig) {
  int i = blockIdx.x * 256 + threadIdx.x;
  float x = pos[i * 3 + 0], y = pos[i * 3 + 1], z = pos[i * 3 + 2];
  int c = cell_of(x, y, z);
  int slot = atomicAdd(&cursor[c], 1);  // within-cell order arbitrary: selections
  spx[slot] = x; spy[slot] = y;         // depend only on (distance, orig idx)
  spz[slot] = z; sorig[slot] = i;
}

__device__ __forceinline__ float f4get(const float4& v, int e) {
  return e == 0 ? v.x : e == 1 ? v.y : e == 2 ? v.z : v.w;  // folds under unroll
}

// ---------------------------------------------------------------------------
// FPS: single workgroup (all sync via LDS barriers — no cross-XCD traffic).
// 1024 threads x 32 sorted points. Per thread: min_d[32] in VGPRs, bucket bbox
// in VGPRs, exact bucket (max, slot, coords) tuple carried across iterations.
// Cull: if bbox-lower-bound dist^2 >= bucket max min_d, nothing can change
// (d >= lb >= md for every point) — bitwise exact skip; 2e-6 rel margin covers
// f32 rounding of lb vs the reference's d. Distances use __fmul_rn/__fadd_rn
// (no fma) to match the reference rounding exactly.
// ---------------------------------------------------------------------------
__global__ __launch_bounds__(1024) void k_fps(
    const float* __restrict__ spx, const float* __restrict__ spy,
    const float* __restrict__ spz, const int* __restrict__ sorig,
    const float* __restrict__ pos, int* __restrict__ fps_idx) {
  const int tid = threadIdx.x;
  const int lane = tid & 63;
  const int wid = tid >> 6;
  const int base = tid * 32;

  __shared__ float s_cx, s_cy, s_cz;
  __shared__ float s_tv[16], s_tx[16], s_ty[16], s_tz[16];
  __shared__ int s_ts[16];
  __shared__ int s_slot[M_CL];  // 32 KB: winner slots; orig-idx resolved in epilogue

  float md[32];
#pragma unroll
  for (int j = 0; j < 32; ++j) md[j] = 3.0e38f;

  const float4* px4 = (const float4*)(spx + base);
  const float4* py4 = (const float4*)(spy + base);
  const float4* pz4 = (const float4*)(spz + base);

  float bnx = 3e38f, bny = 3e38f, bnz = 3e38f;
  float bxx = -3e38f, bxy = -3e38f, bxz = -3e38f;
#pragma unroll
  for (int c = 0; c < 8; ++c) {
    float4 X = px4[c], Y = py4[c], Z = pz4[c];
    bnx = fminf(bnx, fminf(fminf(X.x, X.y), fminf(X.z, X.w)));
    bxx = fmaxf(bxx, fmaxf(fmaxf(X.x, X.y), fmaxf(X.z, X.w)));
    bny = fminf(bny, fminf(fminf(Y.x, Y.y), fminf(Y.z, Y.w)));
    bxy = fmaxf(bxy, fmaxf(fmaxf(Y.x, Y.y), fmaxf(Y.z, Y.w)));
    bnz = fminf(bnz, fminf(fminf(Z.x, Z.y), fminf(Z.z, Z.w)));
    bxz = fmaxf(bxz, fmaxf(fmaxf(Z.x, Z.y), fmaxf(Z.z, Z.w)));
  }

  float val = -1.0f; int slot = base;      // bucket's exact (max, argmax) tuple
  float vx = 0.f, vy = 0.f, vz = 0.f;      // coords of argmax point (for broadcast)
  float mymax = 3.0e38f;

  if (tid == 0) { s_cx = pos[0]; s_cy = pos[1]; s_cz = pos[2]; }  // start = index 0

  for (int m = 1; m < M_CL; ++m) {
    __syncthreads();  // makes s_c* (prev iter) visible; fences s_t* reuse
    float cx = s_cx, cy = s_cy, cz = s_cz;
    float dl = fmaxf(fmaxf(bnx - cx, cx - bxx), 0.0f);
    float dm = fmaxf(fmaxf(bny - cy, cy - bxy), 0.0f);
    float dn = fmaxf(fmaxf(bnz - cz, cz - bxz), 0.0f);
    float lb = dl * dl + dm * dm + dn * dn;
    if (lb < mymax * 1.000002f) {  // dirty bucket: recompute exactly
      float nv = -1.0f; int ns = base;
      float nx = 0.f, ny = 0.f, nz = 0.f;
#pragma unroll
      for (int c = 0; c < 8; ++c) {
        float4 X = px4[c], Y = py4[c], Z = pz4[c];
#pragma unroll
        for (int e = 0; e < 4; ++e) {
          const int j = c * 4 + e;
          float px_ = f4get(X, e), py_ = f4get(Y, e), pz_ = f4get(Z, e);
          float dx = px_ - cx, dy = py_ - cy, dz = pz_ - cz;
          float d = __fadd_rn(__fadd_rn(__fmul_rn(dx, dx), __fmul_rn(dy, dy)),
                              __fmul_rn(dz, dz));
          float mm = fminf(md[j], d);
          md[j] = mm;
          if (mm > nv) { nv = mm; ns = base + j; nx = px_; ny = py_; nz = pz_; }
        }
      }
      mymax = nv; val = nv; slot = ns; vx = nx; vy = ny; vz = nz;
    }
    // block argmax of (val, slot, x, y, z); culled threads contribute exact stale tuple
    float rv = val; int rs = slot; float rx = vx, ry = vy, rz = vz;
#pragma unroll
    for (int o = 32; o > 0; o >>= 1) {
      float ov = __shfl_xor(rv, o);
      int os = __shfl_xor(rs, o);
      float ox = __shfl_xor(rx, o), oy = __shfl_xor(ry, o), oz = __shfl_xor(rz, o);
      if (ov > rv) { rv = ov; rs = os; rx = ox; ry = oy; rz = oz; }
    }
    if (lane == 0) { s_tv[wid] = rv; s_ts[wid] = rs; s_tx[wid] = rx; s_ty[wid] = ry; s_tz[wid] = rz; }
    __syncthreads();
    if (wid == 0) {
      float fv = lane < 16 ? s_tv[lane] : -2.0f;
      int fs = lane < 16 ? s_ts[lane] : 0;
      float fx = lane < 16 ? s_tx[lane] : 0.f;
      float fy = lane < 16 ? s_ty[lane] : 0.f;
      float fz = lane < 16 ? s_tz[lane] : 0.f;
#pragma unroll
      for (int o = 8; o > 0; o >>= 1) {
        float ov = __shfl_xor(fv, o);
        int os = __shfl_xor(fs, o);
        float ox = __shfl_xor(fx, o), oy = __shfl_xor(fy, o), oz = __shfl_xor(fz, o);
        if (ov > fv) { fv = ov; fs = os; fx = ox; fy = oy; fz = oz; }
      }
      if (lane == 0) { s_cx = fx; s_cy = fy; s_cz = fz; s_slot[m] = fs; }
    }
  }
  __syncthreads();
  for (int i = tid; i < M_CL; i += 1024)
    fps_idx[i] = (i == 0) ? 0 : sorig[s_slot[i]];
}

// ---------------------------------------------------------------------------
// GEMM h = x@W + b (f32 vector ALU; no fp32 MFMA on CDNA4). 64x64 tile,
// 4x4 per thread. LDS: as[64][131] (pad 131: 2-way bank pattern on a-reads),
// bs staged in two 64-k phases to stay under the 64 KB static LDS limit.
// ---------------------------------------------------------------------------
__global__ __launch_bounds__(256) void k_gemm(
    const float* __restrict__ x, const float* __restrict__ W,
    const float* __restrict__ bias, float* __restrict__ h) {
  __shared__ float as[64 * 131];
  __shared__ float bs[64 * 64];
  const int tid = threadIdx.x;
  const int r0 = blockIdx.x * 64;
  const int c0 = blockIdx.y * 64;
  const float4* xg = (const float4*)(x + (size_t)r0 * C_IN);
#pragma unroll
  for (int i = 0; i < 8; ++i) {
    int f = tid + i * 256;
    float4 v = xg[f];
    int rr = f >> 5, kk = (f & 31) << 2;
    float* dst = as + rr * 131 + kk;
    dst[0] = v.x; dst[1] = v.y; dst[2] = v.z; dst[3] = v.w;
  }
  const int tr = tid & 15, tc = tid >> 4;
  float acc[4][4];
#pragma unroll
  for (int j = 0; j < 4; ++j)
#pragma unroll
    for (int i = 0; i < 4; ++i) acc[j][i] = 0.f;

  for (int ph = 0; ph < 2; ++ph) {
    __syncthreads();
#pragma unroll
    for (int i = 0; i < 4; ++i) {
      int f = tid + i * 256;
      int kk = f >> 4, cc = (f & 15) << 2;
      float4 v = *(const float4*)(W + (size_t)(ph * 64 + kk) * C_OUTC + c0 + cc);
      *(float4*)(bs + kk * 64 + cc) = v;
    }
    __syncthreads();
#pragma unroll 4
    for (int k = 0; k < 64; ++k) {
      int kg = ph * 64 + k;
      float a0 = as[(tr * 4 + 0) * 131 + kg];
      float a1 = as[(tr * 4 + 1) * 131 + kg];
      float a2 = as[(tr * 4 + 2) * 131 + kg];
      float a3 = as[(tr * 4 + 3) * 131 + kg];
      float4 bv = *(const float4*)(bs + k * 64 + tc * 4);
      acc[0][0] += a0 * bv.x; acc[0][1] += a0 * bv.y; acc[0][2] += a0 * bv.z; acc[0][3] += a0 * bv.w;
      acc[1][0] += a1 * bv.x; acc[1][1] += a1 * bv.y; acc[1][2] += a1 * bv.z; acc[1][3] += a1 * bv.w;
      acc[2][0] += a2 * bv.x; acc[2][1] += a2 * bv.y; acc[2][2] += a2 * bv.z; acc[2][3] += a2 * bv.w;
      acc[3][0] += a3 * bv.x; acc[3][1] += a3 * bv.y; acc[3][2] += a3 * bv.z; acc[3][3] += a3 * bv.w;
    }
  }
  float4 bb = *(const float4*)(bias + c0 + tc * 4);
#pragma unroll
  for (int j = 0; j < 4; ++j) {
    int r = r0 + tr * 4 + j;
    float4 o;
    o.x = acc[j][0] + bb.x; o.y = acc[j][1] + bb.y;
    o.z = acc[j][2] + bb.z; o.w = acc[j][3] + bb.w;
    *(float4*)(h + (size_t)r * C_OUTC + c0 + tc * 4) = o;
  }
}

__global__ void k_bnstats(const float* __restrict__ h, float* __restrict__ bnsum,
                          float* __restrict__ bnsq) {
  int c = threadIdx.x;
  int r0 = blockIdx.x * 128;
  float s = 0.f, q = 0.f;
  for (int r = 0; r < 128; ++r) {
    float v = h[(size_t)(r0 + r) * C_OUTC + c];
    s += v; q += v * v;
  }
  atomicAdd(&bnsum[c], s);
  atomicAdd(&bnsq[c], q);
}

__global__ void k_bnfinal(const float* __restrict__ bnsum, const float* __restrict__ bnsq,
                          const float* __restrict__ gamma, const float* __restrict__ beta,
                          float* __restrict__ scale, float* __restrict__ shift) {
  int c = threadIdx.x;
  float mu = bnsum[c] * (1.0f / 32768.0f);
  float var = bnsq[c] * (1.0f / 32768.0f) - mu * mu;
  float rs = rsqrtf(var + 1e-5f);
  float sc = gamma[c] * rs;
  scale[c] = sc;
  shift[c] = beta[c] - mu * sc;
}

// ---------------------------------------------------------------------------
// KNN + fused BN-affine/relu/max gather. One query per wave; lanes keep sorted
// per-lane top-16 over LDS-staged pos tiles; 16 wave-min extraction rounds
// (lex tie-break (d, idx) — matches top_k stable lowest-index) fused with the
// h-row gather. relu(max(affine(h))) == reference max(relu(affine(h))).
// ---------------------------------------------------------------------------
__global__ __launch_bounds__(256) void k_knn(
    const float* __restrict__ pos, const int* __restrict__ fps_idx,
    const float* __restrict__ h, const float* __restrict__ scale,
    const float* __restrict__ shift, const int* __restrict__ batch,
    float* __restrict__ out) {
  __shared__ float tx[2048], ty[2048], tz[2048];
  __shared__ float mbd[4][1088];  // 64 lanes * 17 (16 + sentinel), pad-17: conflict-free
  __shared__ int mbi[4][1088];
  const int tid = threadIdx.x, lane = tid & 63, wid = tid >> 6;
  const int m = blockIdx.x * 4 + wid;
  const int center = fps_idx[m];
  const float qx = pos[center * 3 + 0];
  const float qy = pos[center * 3 + 1];
  const float qz = pos[center * 3 + 2];
  float qd[16]; int qi[16];
#pragma unroll
  for (int r = 0; r < 16; ++r) { qd[r] = 3.0e38f; qi[r] = 0; }

  for (int t = 0; t < 16; ++t) {
    __syncthreads();
#pragma unroll
    for (int i = 0; i < 24; ++i) {
      int f = t * 6144 + tid + i * 256;
      float v = pos[f];
      int g = f / 3;
      int d3 = f - g * 3;
      int loc = g - t * 2048;
      if (d3 == 0) tx[loc] = v; else if (d3 == 1) ty[loc] = v; else tz[loc] = v;
    }
    __syncthreads();
    for (int s = 0; s < 32; ++s) {
      int p = s * 64 + lane;
      float dx = tx[p] - qx, dy = ty[p] - qy, dz = tz[p] - qz;
      float d = dx * dx + dy * dy + dz * dz;
      if (d < qd[15]) {
        float cv = d; int ci = t * 2048 + p;
#pragma unroll
        for (int r = 0; r < 16; ++r) {
          bool take = cv < qd[r];
          float od = qd[r]; int oi = qi[r];
          qd[r] = take ? cv : od;
          qi[r] = take ? ci : oi;
          cv = take ? od : cv;
          ci = take ? oi : ci;
        }
      }
    }
  }
  float* md_ = &mbd[wid][0]; int* mi_ = &mbi[wid][0];
#pragma unroll
  for (int r = 0; r < 16; ++r) { md_[lane * 17 + r] = qd[r]; mi_[lane * 17 + r] = qi[r]; }
  md_[lane * 17 + 16] = 3.0e38f; mi_[lane * 17 + 16] = 0x7fffffff;
  // wave-local LDS region: no __syncthreads needed (compiler waits lgkmcnt)
  float4 sc4 = *(const float4*)(scale + lane * 4);
  float4 sh4 = *(const float4*)(shift + lane * 4);
  float ax = -3e38f, ay = -3e38f, az = -3e38f, aw = -3e38f;
  int head = 0;
  for (int r = 0; r < 16; ++r) {
    float v = md_[lane * 17 + head];
    int vi = mi_[lane * 17 + head];
    int wl = lane;
#pragma unroll
    for (int o = 32; o > 0; o >>= 1) {
      float ov = __shfl_xor(v, o);
      int ovi = __shfl_xor(vi, o);
      int owl = __shfl_xor(wl, o);
      bool take = (ov < v) || (ov == v && ovi < vi);  // total order: all lanes agree
      v = take ? ov : v; vi = take ? ovi : vi; wl = take ? owl : wl;
    }
    if (wl == lane) head++;
    const float4 hv = *(const float4*)(h + (size_t)vi * C_OUTC + lane * 4);
    ax = fmaxf(ax, sc4.x * hv.x + sh4.x);
    ay = fmaxf(ay, sc4.y * hv.y + sh4.y);
    az = fmaxf(az, sc4.z * hv.z + sh4.z);
    aw = fmaxf(aw, sc4.w * hv.w + sh4.w);
  }
  float4 o4;
  o4.x = fmaxf(ax, 0.f); o4.y = fmaxf(ay, 0.f);
  o4.z = fmaxf(az, 0.f); o4.w = fmaxf(aw, 0.f);
  *(float4*)(out + (size_t)m * C_OUTC + lane * 4) = o4;
  if (lane == 0) {
    float* sp = out + (size_t)M_CL * C_OUTC;
    sp[m * 3 + 0] = qx; sp[m * 3 + 1] = qy; sp[m * 3 + 2] = qz;
    int* sb = (int*)(out + (size_t)M_CL * C_OUTC + (size_t)M_CL * 3);
    sb[m] = batch[center];  // int bits; 0 == 0.0f bitwise either way
  }
}

extern "C" void kernel_launch(void* const* d_in, const int* in_sizes, int n_in,
                              void* d_out, int out_size, void* d_ws, size_t ws_size,
                              hipStream_t stream) {
  const float* x = (const float*)d_in[0];
  const float* pos = (const float*)d_in[1];
  const int* batch = (const int*)d_in[2];
  const float* W = (const float*)d_in[3];
  const float* b = (const float*)d_in[4];
  const float* gamma = (const float*)d_in[5];
  const float* beta = (const float*)d_in[6];
  float* out = (float*)d_out;

  // workspace layout (element offsets; all 256-element aligned)
  float* wsf = (float*)d_ws;
  int* hist = (int*)wsf;                 // 4096
  float* bnsum = wsf + 4096;             // 256
  float* bnsq = wsf + 4352;              // 256
  float* scale = wsf + 4608;             // 256
  float* shift = wsf + 4864;             // 256
  int* cursor = (int*)(wsf + 5120);      // 4096
  int* fps_idx = (int*)(wsf + 9216);     // 8192
  float* spx = wsf + 17408;              // 32768
  float* spy = wsf + 50176;              // 32768
  float* spz = wsf + 82944;              // 32768
  int* sorig = (int*)(wsf + 115712);     // 32768
  float* h = wsf + 148480;               // 32768*256  (~34.1 MB total)

  hipMemsetAsync(d_ws, 0, 4608 * sizeof(float), stream);  // hist + bn accumulators

  k_hist<<<128, 256, 0, stream>>>(pos, hist);
  k_scan<<<1, 1024, 0, stream>>>(hist, cursor);
  k_scatter<<<128, 256, 0, stream>>>(pos, cursor, spx, spy, spz, sorig);
  k_gemm<<<dim3(512, 4), 256, 0, stream>>>(x, W, b, h);
  k_bnstats<<<256, 256, 0, stream>>>(h, bnsum, bnsq);
  k_bnfinal<<<1, 256, 0, stream>>>(bnsum, bnsq, gamma, beta, scale, shift);
  k_fps<<<1, 1024, 0, stream>>>(spx, spy, spz, sorig, pos, fps_idx);
  k_knn<<<2048, 256, 0, stream>>>(pos, fps_idx, h, scale, shift, batch, out);
}